// Round 11
// baseline (157.244 us; speedup 1.0000x reference)
//
#include <hip/hip_runtime.h>

// R18: R17's slab structure with the TAIL FULLY PARALLELIZED across all
// 4 waves (R17 post-mortem: it parallelized only the token phase and made
// the tail serial on wave 0 behind barriers -> +5us vs R14).
//  - phase 1 (all 4 waves): slab staging, token-MLP partials, cat pass
//  - emb-hist: 95 rows split across 8 half-waves (rows 24w+2r+h),
//    wave-uniform table-select (SGPR branches), LDS float atomics to sPool;
//    wave 0 adds the binary-vocab closed form
//  - 32x32 second layers: k-split across waves (8 k each, both matrices
//    via half-wave), atomics; wave 0 folds bias
//  - fc1: 256 threads = 64 outputs x 4 k-quarters (32 FMA each),
//    partials in sF; wave 0 combines + fc2 butterfly
//  - 4 barriers; __launch_bounds__(256,8) -> <=64 VGPR, 32 waves/CU
// Algebra unchanged: histogram-weighted table sums, binary-vocab counts =
// index sums, pooling commutes with the 32x32 second layers.

#define BDIM 256

__device__ __forceinline__ void gld16(const void* g, void* l) {
    __builtin_amdgcn_global_load_lds((__attribute__((address_space(1))) void*)g,
                                     (__attribute__((address_space(3))) void*)l,
                                     16, 0, 0);
}

__global__ __launch_bounds__(BDIM, 8)
void mlpreg_kernel(const float* __restrict__ cont_p,
                   const float* __restrict__ cont_c,
                   const int* __restrict__ cat_p,
                   const int* __restrict__ cat_c,
                   const int* __restrict__ lengths,
                   const float* __restrict__ w_p1, const float* __restrict__ b_p1,
                   const float* __restrict__ w_p2, const float* __restrict__ b_p2,
                   const float* __restrict__ w_c1, const float* __restrict__ b_c1,
                   const float* __restrict__ w_c2, const float* __restrict__ b_c2,
                   const float* __restrict__ emb_g,  const float* __restrict__ emb_k,
                   const float* __restrict__ emb_pr, const float* __restrict__ emb_j,
                   const float* __restrict__ emb_r,  const float* __restrict__ emb_pl,
                   const float* __restrict__ emb_a,
                   const float* __restrict__ w_fc1, const float* __restrict__ b_fc1,
                   const float* __restrict__ w_fc2, const float* __restrict__ b_fc2,
                   float* __restrict__ out)
{
    constexpr int S = 256;
    __shared__ __align__(16) float sPc[4][192];   // 3072 B slab cont_p
    __shared__ __align__(16) float sCc[4][128];   // 2048 B slab cont_c
    __shared__ __align__(16) int   sKp[4][320];   // 5120 B slab cat_p
    __shared__ int   hist[96];                    //  384 B
    __shared__ float sAccW[4][64];                // 1024 B per-wave partials
    __shared__ int   sSums[4][3];                 //   48 B
    __shared__ float sPool[128];                  //  512 B (atomic-accumulated)
    __shared__ float sF[4][64];                   // 1024 B fc1 partials
    // ~13.2 KB -> wave-capped 8 WGs/CU = 32 waves/CU

    const int tid  = threadIdx.x;
    const int wid  = tid >> 6;
    const int lane = tid & 63;
    const int ch   = lane & 31, h = lane >> 5;
    const int b    = blockIdx.x;

    int L = lengths[b]; L = (L < 1) ? 1 : (L > S ? S : L);
    const float Lf = (float)L, invL = 1.0f / Lf;

    const int t0 = wid << 6;
    const int nt = (L - t0 < 64) ? (L - t0) : 64;   // may be <= 0

    if (tid < 96)  hist[tid] = 0;
    if (tid < 128) sPool[tid] = 0.f;

    // ---- staging: each wave stages its own slab (exec-masked gld16) ----
    if (nt > 0) {
        const char* gp = (const char*)(cont_p + (size_t)b * 768  + t0 * 3);
        const char* gc = (const char*)(cont_c + (size_t)b * 512  + t0 * 2);
        const char* gk = (const char*)(cat_p  + (size_t)b * 1280 + t0 * 5);
        const int lo = 16 * lane;
        const int bP = 12 * nt, bC = 8 * nt, bK = 20 * nt;
        if (lo < bP)        gld16(gp + lo,        (char*)sPc[wid]);
        if (lo < bC)        gld16(gc + lo,        (char*)sCc[wid]);
        if (lo < bK)        gld16(gk + lo,        (char*)sKp[wid]);
        if (1024 + lo < bK) gld16(gk + 1024 + lo, (char*)sKp[wid] + 1024);
    }
    // cat_c: one token per lane, int2 register load (coalesced)
    int2 qc; qc.x = 0; qc.y = 0;
    if (lane < nt) qc = ((const int2*)(cat_c + (size_t)b * 512))[t0 + lane];

    // ---- first-layer weights (all waves) ----
    const float wp0 = w_p1[ch], wp1v = w_p1[32 + ch], wp2v = w_p1[64 + ch], bp = b_p1[ch];
    const float wc0 = w_c1[ch], wc1v = w_c1[32 + ch], bc = b_c1[ch];
    // ---- wave-0-only preloads ----
    float eg0 = 0, eg1 = 0, ek0 = 0, ek1 = 0, er0 = 0, er1 = 0;
    float bias2 = 0, bf1 = 0, bq0 = 0, bq1 = 0;
    float2 wf2; wf2.x = 0; wf2.y = 0;
    if (wid == 0) {
        eg0 = emb_g[ch];  eg1 = emb_g[32 + ch];
        ek0 = emb_k[ch];  ek1 = emb_k[32 + ch];
        er0 = emb_pr[ch]; er1 = emb_pr[32 + ch];
        bias2 = h ? b_c2[ch] : b_p2[ch];
        bf1 = b_fc1[lane];
        wf2 = *(const float2*)&w_fc2[2 * lane];
        bq0 = b_fc2[0]; bq1 = b_fc2[1];
    }

    __syncthreads();   // B1: vmcnt drain + hist/sPool zeroed

    // ---- token relu-MLP on own slab (channel-per-lane, half-wave split) ----
    float aP = 0.f, aC = 0.f;
    if (nt > 0) {
        const int gf = nt >> 2;
        const int gh = (gf + 1) >> 1;
        const float4* tp4 = (const float4*)sPc[wid];
        const float4* tc4 = (const float4*)sCc[wid];
        #pragma unroll 4
        for (int i = 0; i < gh; ++i) {
            const int g = h ? gh + i : i;
            if (g < gf) {
                float4 a  = tp4[3 * g], bb = tp4[3 * g + 1], cc = tp4[3 * g + 2];
                float4 d  = tc4[2 * g], ee = tc4[2 * g + 1];
                float p0 = fmaxf(fmaf(a.x,  wp0, fmaf(a.y,  wp1v, fmaf(a.z,  wp2v, bp))), 0.f);
                float p1 = fmaxf(fmaf(a.w,  wp0, fmaf(bb.x, wp1v, fmaf(bb.y, wp2v, bp))), 0.f);
                float p2 = fmaxf(fmaf(bb.z, wp0, fmaf(bb.w, wp1v, fmaf(cc.x, wp2v, bp))), 0.f);
                float p3 = fmaxf(fmaf(cc.y, wp0, fmaf(cc.z, wp1v, fmaf(cc.w, wp2v, bp))), 0.f);
                aP += (p0 + p1) + (p2 + p3);
                float q0 = fmaxf(fmaf(d.x,  wc0, fmaf(d.y,  wc1v, bc)), 0.f);
                float q1 = fmaxf(fmaf(d.z,  wc0, fmaf(d.w,  wc1v, bc)), 0.f);
                float q2 = fmaxf(fmaf(ee.x, wc0, fmaf(ee.y, wc1v, bc)), 0.f);
                float q3 = fmaxf(fmaf(ee.z, wc0, fmaf(ee.w, wc1v, bc)), 0.f);
                aC += (q0 + q1) + (q2 + q3);
            }
        }
        const int rem = nt & 3;
        if (h == 0 && rem) {
            const float* tp = sPc[wid] + 12 * gf;
            const float* tc = sCc[wid] + 8 * gf;
            for (int r = 0; r < rem; ++r) {
                aP += fmaxf(fmaf(tp[3*r], wp0, fmaf(tp[3*r+1], wp1v, fmaf(tp[3*r+2], wp2v, bp))), 0.f);
                aC += fmaxf(fmaf(tc[2*r], wc0, fmaf(tc[2*r+1], wc1v, bc)), 0.f);
            }
        }
    }
    aP += __shfl_xor(aP, 32);
    aC += __shfl_xor(aC, 32);
    sAccW[wid][lane] = h ? aC : aP;   // un-normalized slab partial

    // ---- cat pass: one token per lane from LDS; shared hist atomics ----
    int v0 = 0, v1 = 0, v2 = 0;
    if (lane < nt) {
        const int* kp = sKp[wid] + 5 * lane;
        v0 = kp[0]; v1 = kp[1]; v2 = kp[2];
        const int v3 = kp[3], v4 = kp[4];
        atomicAdd(&hist[v3], 1);
        atomicAdd(&hist[11 + v4], 1);
        atomicAdd(&hist[45 + qc.x], 1);
        atomicAdd(&hist[64 + qc.y], 1);
    }
    #pragma unroll
    for (int d = 32; d; d >>= 1) {
        v0 += __shfl_xor(v0, d); v1 += __shfl_xor(v1, d); v2 += __shfl_xor(v2, d);
    }
    if (lane == 0) { sSums[wid][0] = v0; sSums[wid][1] = v1; sSums[wid][2] = v2; }
    __syncthreads();   // B2: partials + hist complete

    // ---- emb-hist, parallel over 8 half-waves (rows 24w + 2r + h) ----
    {
        float Ap = 0.f, Ac = 0.f;
        if (wid == 0 && h == 0) {
            const int sg = sSums[0][0] + sSums[1][0] + sSums[2][0] + sSums[3][0];
            const int sk = sSums[0][1] + sSums[1][1] + sSums[2][1] + sSums[3][1];
            const int sp = sSums[0][2] + sSums[1][2] + sSums[2][2] + sSums[3][2];
            float fg = (float)sg, fk = (float)sk, fp = (float)sp;
            Ap = fmaf(Lf - fg, eg0, fg * eg1) + fmaf(Lf - fk, ek0, fk * ek1)
               + fmaf(Lf - fp, er0, fp * er1);
        }
        const int base = 24 * wid;
        #pragma unroll
        for (int r = 0; r < 12; ++r) {
            const int rr = base + 2 * r + h;   // wave+half uniform
            if (rr < 95) {
                const float* p;
                if (rr < 11)      p = emb_j  + (rr << 5);
                else if (rr < 45) p = emb_r  + ((rr - 11) << 5);
                else if (rr < 64) p = emb_pl + ((rr - 45) << 5);
                else              p = emb_a  + ((rr - 64) << 5);
                const float t = (float)hist[rr];
                const float wv = p[ch];
                if (rr < 45) Ap = fmaf(t, wv, Ap);
                else         Ac = fmaf(t, wv, Ac);
            }
        }
        atomicAdd(&sPool[ch],      Ap * (invL * 0.2f));
        atomicAdd(&sPool[32 + ch], Ac * (invL * 0.5f));
    }

    // ---- 32x32 second layers: k-split across waves (8 k each) ----
    {
        const float* W2 = h ? w_c2 : w_p2;
        float partial = 0.f;
        #pragma unroll
        for (int k = 0; k < 8; ++k) {
            const int kk = 8 * wid + k;
            const int a = (h << 5) + kk;
            const float ak = (sAccW[0][a] + sAccW[1][a]) + (sAccW[2][a] + sAccW[3][a]);
            partial = fmaf(ak, W2[(kk << 5) + ch], partial);
        }
        float val = partial * invL;
        if (wid == 0) val += bias2;          // fold bias exactly once
        atomicAdd(&sPool[64 + (h << 5) + ch], val);
    }
    __syncthreads();   // B3: sPool complete

    // ---- fc1: 64 outputs x 4 k-quarters, 32 FMA per thread ----
    {
        const int o = lane, q = wid;
        float x = 0.f;
        const int k0 = q << 5;
        #pragma unroll 8
        for (int k = 0; k < 32; ++k) {
            x = fmaf(sPool[k0 + k], w_fc1[(size_t)(k0 + k) * 64 + o], x);
        }
        sF[q][o] = x;
    }
    __syncthreads();   // B4: fc1 partials ready

    // ---- combine + fc2 butterfly (wave 0) ----
    if (wid == 0) {
        float x = (sF[0][lane] + sF[1][lane]) + (sF[2][lane] + sF[3][lane]) + bf1;
        float hv = fmaxf(x, 0.f);
        float q0 = hv * wf2.x, q1 = hv * wf2.y;
        #pragma unroll
        for (int d = 32; d; d >>= 1) {
            q0 += __shfl_xor(q0, d); q1 += __shfl_xor(q1, d);
        }
        if (lane == 0) {
            float2 o2;
            o2.x = fmaxf(q0 + bq0, 0.f);
            o2.y = fmaxf(q1 + bq1, 0.f);
            *(float2*)&out[(size_t)b * 2] = o2;   // 8B-aligned per-row store
        }
    }
}

extern "C" void kernel_launch(void* const* d_in, const int* in_sizes, int n_in,
                              void* d_out, int out_size, void* d_ws, size_t ws_size,
                              hipStream_t stream) {
    const float* cont_p = (const float*)d_in[0];
    const float* cont_c = (const float*)d_in[1];
    const int*   cat_p  = (const int*)d_in[2];
    const int*   cat_c  = (const int*)d_in[3];
    const int*   lens   = (const int*)d_in[4];
    const float* w_p1   = (const float*)d_in[5];
    const float* b_p1   = (const float*)d_in[6];
    const float* w_p2   = (const float*)d_in[7];
    const float* b_p2   = (const float*)d_in[8];
    const float* w_c1   = (const float*)d_in[9];
    const float* b_c1   = (const float*)d_in[10];
    const float* w_c2   = (const float*)d_in[11];
    const float* b_c2   = (const float*)d_in[12];
    const float* emb_g  = (const float*)d_in[13];
    const float* emb_k  = (const float*)d_in[14];
    const float* emb_pr = (const float*)d_in[15];
    const float* emb_j  = (const float*)d_in[16];
    const float* emb_r  = (const float*)d_in[17];
    const float* emb_pl = (const float*)d_in[18];
    const float* emb_a  = (const float*)d_in[19];
    const float* w_fc1  = (const float*)d_in[20];
    const float* b_fc1  = (const float*)d_in[21];
    const float* w_fc2  = (const float*)d_in[22];
    const float* b_fc2  = (const float*)d_in[23];
    float* out = (float*)d_out;

    hipLaunchKernelGGL(mlpreg_kernel, dim3(4096), dim3(BDIM), 0, stream,
                       cont_p, cont_c, cat_p, cat_c, lens,
                       w_p1, b_p1, w_p2, b_p2, w_c1, b_c1, w_c2, b_c2,
                       emb_g, emb_k, emb_pr, emb_j, emb_r, emb_pl, emb_a,
                       w_fc1, b_fc1, w_fc2, b_fc2, out);
}